// Round 5
// baseline (224.689 us; speedup 1.0000x reference)
//
#include <hip/hip_runtime.h>
#include <math.h>

#define BATCH 2
#define TSEQ 4096
#define DM 768
#define HEADS 4
#define DHEAD 64
#define DIMQ 256                  // HEADS*DHEAD
#define MROWS (BATCH*TSEQ)        // 8192
#define CHUNK 64
#define NCHUNK (TSEQ/CHUNK)       // 64
#define STATE (DHEAD*DHEAD + DHEAD)  // 4160
#define KSPLIT (DM*2)             // 1536 stored k-cols for x/wt: [hi 768 | lo 768]
#define KS2 (DIMQ*2)              // 512 stored k-cols for attn/wot: [hi 256 | lo 256]

typedef __attribute__((ext_vector_type(8))) short bf16x8;
typedef __attribute__((ext_vector_type(4))) float f32x4;

__device__ __forceinline__ float act_elu1(float x){ return x > 0.f ? x + 1.f : expf(x); }
__device__ __forceinline__ float act_sig(float x){ return 1.f/(1.f + expf(-x)); }

__device__ __forceinline__ void fma4(float4& o, float a, const float4& b){
    o.x = fmaf(a, b.x, o.x); o.y = fmaf(a, b.y, o.y);
    o.z = fmaf(a, b.z, o.z); o.w = fmaf(a, b.w, o.w);
}
__device__ __forceinline__ float comp4(const float4& v, int u){
    return u==0 ? v.x : u==1 ? v.y : u==2 ? v.z : v.w;
}

// round-to-nearest-even fp32 -> bf16
__device__ __forceinline__ unsigned short bf16_rne(float f){
    unsigned u = __float_as_uint(f);
    u += 0x7FFFu + ((u >> 16) & 1u);
    return (unsigned short)(u >> 16);
}

// NOTE: LDS dest is wave-uniform base + lane*16B (m104/m108). Every call site
// must pass a dest whose per-lane address is exactly base + lane*16.
__device__ __forceinline__ void gload_lds16(const void* g, void* l){
    __builtin_amdgcn_global_load_lds(
        (const __attribute__((address_space(1))) unsigned char*)g,
        (__attribute__((address_space(3))) unsigned char*)l, 16, 0, 0);
}

// ---------------------------------------------------------------------------
// Kernel 0: merged prep. Blocks:
//   [0, 8192)     : split x row -> xs [hi 768 | lo 768]
//   [8192, 8480)  : split/transpose Wq|Wk|Wv|Wg 64x64 tile -> wt
// ---------------------------------------------------------------------------
__global__ __launch_bounds__(256)
void prep(const float* __restrict__ x,
          const float* __restrict__ Wq, const float* __restrict__ Wk,
          const float* __restrict__ Wv, const float* __restrict__ Wg,
          unsigned short* __restrict__ xs, unsigned short* __restrict__ wt)
{
    __shared__ float T[64][65];
    const int bid = blockIdx.x;
    const int t = threadIdx.x;

    if (bid < MROWS) {                       // ---- x split ----
        if (t < 192) {
            const int r = bid;
            const int c = t * 4;
            float4 v = *(const float4*)&x[(size_t)r*DM + c];
            float vv[4] = {v.x, v.y, v.z, v.w};
            unsigned short h[4], l[4];
            #pragma unroll
            for (int j = 0; j < 4; j++){
                h[j] = bf16_rne(vv[j]);
                float hf = __uint_as_float((unsigned)h[j] << 16);
                l[j] = bf16_rne(vv[j] - hf);
            }
            ushort4 h4 = {h[0],h[1],h[2],h[3]}, l4 = {l[0],l[1],l[2],l[3]};
            *(ushort4*)&xs[(size_t)r*KSPLIT + c] = h4;
            *(ushort4*)&xs[(size_t)r*KSPLIT + DM + c] = l4;
        }
        return;
    }

    // ---- weight transpose-split ----
    const int i = bid - MROWS;
    const int n0 = (i % 24)*64, k0 = (i / 24)*64;   // 24 n-tiles x 12 k-tiles
    const float* W; int ldw, c0;
    if      (n0 < 256) { W = Wq; ldw = DIMQ; c0 = n0;       }
    else if (n0 < 512) { W = Wk; ldw = DIMQ; c0 = n0 - 256; }
    else if (n0 < 768) { W = Wv; ldw = DIMQ; c0 = n0 - 512; }
    else               { W = Wg; ldw = DM;   c0 = n0 - 768; }

    const int lr = t >> 4, lc = (t & 15) * 4;
    #pragma unroll
    for (int ii = 0; ii < 4; ii++){
        int r = lr + ii*16;
        float4 v = *(const float4*)&W[(size_t)(k0+r)*ldw + c0 + lc];
        T[r][lc+0]=v.x; T[r][lc+1]=v.y; T[r][lc+2]=v.z; T[r][lc+3]=v.w;
    }
    __syncthreads();
    const int rn = t >> 2, kc = (t & 3) * 16;
    unsigned short hb[16], lb[16];
    #pragma unroll
    for (int j = 0; j < 16; j++){
        float f = T[kc+j][rn];
        hb[j] = bf16_rne(f);
        float hf = __uint_as_float((unsigned)hb[j] << 16);
        lb[j] = bf16_rne(f - hf);
    }
    size_t base = (size_t)(n0+rn)*KSPLIT + k0 + kc;
    #pragma unroll
    for (int q = 0; q < 4; q++){
        ushort4 hv = {hb[q*4],hb[q*4+1],hb[q*4+2],hb[q*4+3]};
        ushort4 lv = {lb[q*4],lb[q*4+1],lb[q*4+2],lb[q*4+3]};
        *(ushort4*)&wt[base + q*4] = hv;
        *(ushort4*)&wt[base + DM + q*4] = lv;
    }
}

// ---------------------------------------------------------------------------
// Kernel 0c: wot (768 x 512 bf16): row n = [hi(Wo[:,n]) 256 | lo 256]
// Launched AFTER gemm_qkvg_mfma (wot aliases then-dead wt region).
// ---------------------------------------------------------------------------
__global__ __launch_bounds__(256)
void split_wo(const float* __restrict__ Wo, unsigned short* __restrict__ wot)
{
    const int n0 = blockIdx.x * 64;   // 12 tiles over 768
    const int k0 = blockIdx.y * 64;   // 4 tiles over 256
    __shared__ float T[64][65];
    const int t = threadIdx.x;
    const int lr = t >> 4, lc = (t & 15) * 4;
    #pragma unroll
    for (int i = 0; i < 4; i++){
        int r = lr + i*16;
        float4 v = *(const float4*)&Wo[(size_t)(k0+r)*DM + n0 + lc];
        T[r][lc+0]=v.x; T[r][lc+1]=v.y; T[r][lc+2]=v.z; T[r][lc+3]=v.w;
    }
    __syncthreads();
    const int rn = t >> 2, kc = (t & 3) * 16;
    unsigned short hb[16], lb[16];
    #pragma unroll
    for (int j = 0; j < 16; j++){
        float f = T[kc+j][rn];
        hb[j] = bf16_rne(f);
        float hf = __uint_as_float((unsigned)hb[j] << 16);
        lb[j] = bf16_rne(f - hf);
    }
    size_t base = (size_t)(n0+rn)*KS2 + k0 + kc;
    #pragma unroll
    for (int q = 0; q < 4; q++){
        ushort4 hv = {hb[q*4],hb[q*4+1],hb[q*4+2],hb[q*4+3]};
        ushort4 lv = {lb[q*4],lb[q*4+1],lb[q*4+2],lb[q*4+3]};
        *(ushort4*)&wot[base + q*4] = hv;
        *(ushort4*)&wot[base + DIMQ + q*4] = lv;
    }
}

// ---------------------------------------------------------------------------
// Kernel 1: fused projection GEMM, single-pass cross-product K-loop.
// Stage x_hi/x_lo/W_hi/W_lo (32 KB) per BK=32 step; 48 MFMA/wave per barrier:
//   acc += xh*wh + xh*wl + xl*wh
// ---------------------------------------------------------------------------
__global__ __launch_bounds__(256, 2)
void gemm_qkvg_mfma(const unsigned short* __restrict__ xs,
                    const unsigned short* __restrict__ wt,
                    float* __restrict__ qws, float* __restrict__ kws,
                    float* __restrict__ vws, float* __restrict__ gws)
{
    __shared__ unsigned short Ah[128*32];
    __shared__ unsigned short Al[128*32];
    __shared__ unsigned short Bh[128*32];
    __shared__ unsigned short Bl[128*32];

    const int m0 = blockIdx.x * 128;
    const int n0 = blockIdx.y * 128;
    const int tid = threadIdx.x;
    const int lane = tid & 63, w = tid >> 6;
    const int wm = (w & 1) * 64, wn = (w >> 1) * 64;
    const int l15 = lane & 15, lq = lane >> 4;

    // dest tid*16B = (wave base) + lane*16B — conforms to global_load_lds
    const int srow = tid >> 2, scq = tid & 3;
    const unsigned short* xr0 = xs + (size_t)(m0+srow)   * KSPLIT + scq*8;
    const unsigned short* xr1 = xs + (size_t)(m0+srow+64)* KSPLIT + scq*8;
    const unsigned short* br0 = wt + (size_t)(n0+srow)   * KSPLIT + scq*8;
    const unsigned short* br1 = wt + (size_t)(n0+srow+64)* KSPLIT + scq*8;

    f32x4 acc[4][4];
    #pragma unroll
    for (int i = 0; i < 4; i++)
        #pragma unroll
        for (int j = 0; j < 4; j++)
            acc[i][j] = (f32x4){0.f, 0.f, 0.f, 0.f};

    #pragma unroll 1
    for (int ks = 0; ks < 24; ks++){
        const int o = ks*32;
        __syncthreads();
        gload_lds16(xr0 + o,      &Ah[tid*8]);
        gload_lds16(xr1 + o,      &Ah[2048 + tid*8]);
        gload_lds16(xr0 + DM + o, &Al[tid*8]);
        gload_lds16(xr1 + DM + o, &Al[2048 + tid*8]);
        gload_lds16(br0 + o,      &Bh[tid*8]);
        gload_lds16(br1 + o,      &Bh[2048 + tid*8]);
        gload_lds16(br0 + DM + o, &Bl[tid*8]);
        gload_lds16(br1 + DM + o, &Bl[2048 + tid*8]);
        __syncthreads();

        bf16x8 ah[4], al[4], bh[4], bl[4];
        #pragma unroll
        for (int im = 0; im < 4; im++){
            ah[im] = *(const bf16x8*)&Ah[(wm + im*16 + l15)*32 + lq*8];
            al[im] = *(const bf16x8*)&Al[(wm + im*16 + l15)*32 + lq*8];
        }
        #pragma unroll
        for (int jn = 0; jn < 4; jn++){
            bh[jn] = *(const bf16x8*)&Bh[(wn + jn*16 + l15)*32 + lq*8];
            bl[jn] = *(const bf16x8*)&Bl[(wn + jn*16 + l15)*32 + lq*8];
        }
        #pragma unroll
        for (int im = 0; im < 4; im++)
            #pragma unroll
            for (int jn = 0; jn < 4; jn++){
                acc[im][jn] = __builtin_amdgcn_mfma_f32_16x16x32_bf16(
                    ah[im], bh[jn], acc[im][jn], 0, 0, 0);
                acc[im][jn] = __builtin_amdgcn_mfma_f32_16x16x32_bf16(
                    ah[im], bl[jn], acc[im][jn], 0, 0, 0);
                acc[im][jn] = __builtin_amdgcn_mfma_f32_16x16x32_bf16(
                    al[im], bh[jn], acc[im][jn], 0, 0, 0);
            }
    }

    // epilogue: C/D layout col = lane&15, row = (lane>>4)*4 + reg
    float* dst; int ld, cb, mode;
    const int bj = blockIdx.y;
    if      (bj < 2) { dst = qws; ld = DIMQ; cb = bj*128;       mode = 1; }
    else if (bj < 4) { dst = kws; ld = DIMQ; cb = (bj-2)*128;   mode = 1; }
    else if (bj < 6) { dst = vws; ld = DIMQ; cb = (bj-4)*128;   mode = 0; }
    else             { dst = gws; ld = DM;   cb = (bj-6)*128;   mode = 2; }

    #pragma unroll
    for (int im = 0; im < 4; im++){
        const int rb = m0 + wm + im*16 + lq*4;
        #pragma unroll
        for (int jn = 0; jn < 4; jn++){
            const int col = cb + wn + jn*16 + l15;
            f32x4 a = acc[im][jn];
            #pragma unroll
            for (int r = 0; r < 4; r++){
                float v0 = a[r];
                float vv = (mode == 1) ? act_elu1(v0)
                         : (mode == 2) ? act_sig(v0) : v0;
                dst[(size_t)(rb + r)*ld + col] = vv;
            }
        }
    }
}

// ---------------------------------------------------------------------------
// Kernel 2: per-chunk state  S[e][d] = sum_s v[s][e]*k[s][d],  z[e] = sum_s k[s][e]
// ---------------------------------------------------------------------------
__global__ __launch_bounds__(256, 2)
void chunk_state(const float* __restrict__ kws, const float* __restrict__ vws,
                 float* __restrict__ Sws)
{
    __shared__ float Ks[64][64];
    __shared__ float Vt[64][68];

    const int blk = blockIdx.x;
    const int c = blk & (NCHUNK-1);
    const int bh = blk >> 6;
    const int b = bh >> 2, h = bh & 3;
    const int row0 = b*TSEQ + c*CHUNK;
    const int col0 = h*DHEAD;
    const int tid = threadIdx.x;

    #pragma unroll
    for (int i = 0; i < 4; i++) {
        int flat = tid + i*256;
        int s = flat >> 4, dq = flat & 15;
        float4 k4 = *(const float4*)&kws[(size_t)(row0+s)*DIMQ + col0 + dq*4];
        *(float4*)&Ks[s][dq*4] = k4;
        float4 v4 = *(const float4*)&vws[(size_t)(row0+s)*DIMQ + col0 + dq*4];
        Vt[dq*4+0][s] = v4.x; Vt[dq*4+1][s] = v4.y;
        Vt[dq*4+2][s] = v4.z; Vt[dq*4+3][s] = v4.w;
    }
    __syncthreads();

    const int e = tid >> 2, d0 = (tid & 3) * 16;
    float4 a0 = {0,0,0,0}, a1 = {0,0,0,0}, a2 = {0,0,0,0}, a3 = {0,0,0,0};
    for (int s = 0; s < 64; s++) {
        float ve = Vt[e][s];
        fma4(a0, ve, *(const float4*)&Ks[s][d0+0]);
        fma4(a1, ve, *(const float4*)&Ks[s][d0+4]);
        fma4(a2, ve, *(const float4*)&Ks[s][d0+8]);
        fma4(a3, ve, *(const float4*)&Ks[s][d0+12]);
    }
    float* Sp = Sws + (size_t)blk * STATE;
    *(float4*)&Sp[e*64 + d0 + 0]  = a0;
    *(float4*)&Sp[e*64 + d0 + 4]  = a1;
    *(float4*)&Sp[e*64 + d0 + 8]  = a2;
    *(float4*)&Sp[e*64 + d0 + 12] = a3;

    if (tid < 64) {
        float z = 0.f;
        for (int s = 0; s < 64; s++) z += Ks[s][tid];
        Sp[4096 + tid] = z;
    }
}

// ---------------------------------------------------------------------------
// Kernel 3: exclusive prefix over chunks; grid (8 bh, 17 slices)
// ---------------------------------------------------------------------------
__global__ __launch_bounds__(256)
void prefix_scan(const float* __restrict__ Sws, float* __restrict__ Pws)
{
    const int bh = blockIdx.x;
    const int i = blockIdx.y*256 + threadIdx.x;
    if (i >= STATE) return;
    const size_t base = (size_t)bh * NCHUNK * STATE;
    float run = 0.f;
    const float* sp = Sws + base + i;
    float* pp = Pws + base + i;
    #pragma unroll 4
    for (int c = 0; c < NCHUNK; c++) {
        pp[(size_t)c * STATE] = run;
        run += sp[(size_t)c * STATE];
    }
}

// ---------------------------------------------------------------------------
// Kernel 4: per-chunk output; writes attn as split-bf16 [hi 256 | lo 256]
// ---------------------------------------------------------------------------
__global__ __launch_bounds__(256, 2)
void chunk_out(const float* __restrict__ qws, const float* __restrict__ kws,
               const float* __restrict__ vws, const float* __restrict__ Pws,
               unsigned short* __restrict__ attn_s)
{
    __shared__ float Qs[64][68];
    __shared__ float Ks[64][64];
    __shared__ float VA[64][68];
    __shared__ float Ps[64][64];
    __shared__ float zP[64];
    __shared__ float dpart[64][4];
    __shared__ float dinv[64];

    const int blk = blockIdx.x;
    const int c = blk & (NCHUNK-1);
    const int bh = blk >> 6;
    const int b = bh >> 2, h = bh & 3;
    const int row0 = b*TSEQ + c*CHUNK;
    const int col0 = h*DHEAD;
    const int tid = threadIdx.x;
    const float* Pp = Pws + (size_t)blk * STATE;

    #pragma unroll
    for (int i = 0; i < 4; i++) {
        int flat = tid + i*256;
        int s = flat >> 4, dq = flat & 15;
        float4 q4 = *(const float4*)&qws[(size_t)(row0+s)*DIMQ + col0 + dq*4];
        Qs[s][dq*4+0] = q4.x; Qs[s][dq*4+1] = q4.y;
        Qs[s][dq*4+2] = q4.z; Qs[s][dq*4+3] = q4.w;
        float4 k4 = *(const float4*)&kws[(size_t)(row0+s)*DIMQ + col0 + dq*4];
        *(float4*)&Ks[s][dq*4] = k4;
        float4 v4 = *(const float4*)&vws[(size_t)(row0+s)*DIMQ + col0 + dq*4];
        VA[dq*4+0][s] = v4.x; VA[dq*4+1][s] = v4.y;
        VA[dq*4+2][s] = v4.z; VA[dq*4+3][s] = v4.w;
        float4 p4 = *(const float4*)&Pp[flat*4];
        *(float4*)&Ps[0][flat*4] = p4;
    }
    if (tid < 16) {
        *(float4*)&zP[tid*4] = *(const float4*)&Pp[4096 + tid*4];
    }
    __syncthreads();

    const int t  = tid >> 2;
    const int qq = tid & 3;
    const int s0 = qq * 16;

    float4 qreg[16];
    #pragma unroll
    for (int eq = 0; eq < 16; eq++) qreg[eq] = *(const float4*)&Qs[t][eq*4];

    float dsum = 0.f;
    for (int i = 0; i < 16; i++) {
        int s = s0 + i;
        if (s <= t) {
            float a = 0.f;
            #pragma unroll
            for (int eq = 0; eq < 16; eq++) {
                float4 k4 = *(const float4*)&Ks[s][eq*4];
                float4 qv = qreg[eq];
                a = fmaf(qv.x, k4.x, a); a = fmaf(qv.y, k4.y, a);
                a = fmaf(qv.z, k4.z, a); a = fmaf(qv.w, k4.w, a);
            }
            dsum += a;
        }
    }
    dpart[t][qq] = dsum;

    float areg[16];
    #pragma unroll
    for (int i = 0; i < 16; i++) areg[i] = 0.f;
    #pragma unroll
    for (int eq = 0; eq < 16; eq++) {
        float4 qv = qreg[eq];
        #pragma unroll
        for (int u = 0; u < 4; u++) {
            int e = eq*4 + u;
            float qe = comp4(qv, u);
            float4 v0 = *(const float4*)&VA[e][s0+0];
            float4 v1 = *(const float4*)&VA[e][s0+4];
            float4 v2 = *(const float4*)&VA[e][s0+8];
            float4 v3 = *(const float4*)&VA[e][s0+12];
            areg[0]=fmaf(qe,v0.x,areg[0]);  areg[1]=fmaf(qe,v0.y,areg[1]);
            areg[2]=fmaf(qe,v0.z,areg[2]);  areg[3]=fmaf(qe,v0.w,areg[3]);
            areg[4]=fmaf(qe,v1.x,areg[4]);  areg[5]=fmaf(qe,v1.y,areg[5]);
            areg[6]=fmaf(qe,v1.z,areg[6]);  areg[7]=fmaf(qe,v1.w,areg[7]);
            areg[8]=fmaf(qe,v2.x,areg[8]);  areg[9]=fmaf(qe,v2.y,areg[9]);
            areg[10]=fmaf(qe,v2.z,areg[10]); areg[11]=fmaf(qe,v2.w,areg[11]);
            areg[12]=fmaf(qe,v3.x,areg[12]); areg[13]=fmaf(qe,v3.y,areg[13]);
            areg[14]=fmaf(qe,v3.z,areg[14]); areg[15]=fmaf(qe,v3.w,areg[15]);
        }
    }
    __syncthreads();

    #pragma unroll
    for (int i4 = 0; i4 < 4; i4++) {
        float4 w;
        w.x = (s0 + i4*4 + 0 <= t) ? areg[i4*4+0] : 0.f;
        w.y = (s0 + i4*4 + 1 <= t) ? areg[i4*4+1] : 0.f;
        w.z = (s0 + i4*4 + 2 <= t) ? areg[i4*4+2] : 0.f;
        w.w = (s0 + i4*4 + 3 <= t) ? areg[i4*4+3] : 0.f;
        *(float4*)&VA[t][s0 + i4*4] = w;
    }
    if (qq == 0) {
        float den = dpart[t][0] + dpart[t][1] + dpart[t][2] + dpart[t][3];
        #pragma unroll
        for (int eq = 0; eq < 16; eq++) {
            float4 z4 = *(const float4*)&zP[eq*4];
            float4 qv = qreg[eq];
            den = fmaf(qv.x, z4.x, den); den = fmaf(qv.y, z4.y, den);
            den = fmaf(qv.z, z4.z, den); den = fmaf(qv.w, z4.w, den);
        }
        den = fmaxf(den, 1e-6f);
        dinv[t] = 1.f / den;
    }
    __syncthreads();

    const int d0 = qq * 16;
    float4 o0 = {0,0,0,0}, o1 = {0,0,0,0}, o2 = {0,0,0,0}, o3 = {0,0,0,0};
    #pragma unroll
    for (int eq = 0; eq < 16; eq++) {
        float4 qv = qreg[eq];
        #pragma unroll
        for (int u = 0; u < 4; u++) {
            int e = eq*4 + u;
            float qe = comp4(qv, u);
            fma4(o0, qe, *(const float4*)&Ps[e][d0+0]);
            fma4(o1, qe, *(const float4*)&Ps[e][d0+4]);
            fma4(o2, qe, *(const float4*)&Ps[e][d0+8]);
            fma4(o3, qe, *(const float4*)&Ps[e][d0+12]);
        }
    }
    for (int s = 0; s < 64; s++) {
        float a = VA[t][s];
        fma4(o0, a, *(const float4*)&Ks[s][d0+0]);
        fma4(o1, a, *(const float4*)&Ks[s][d0+4]);
        fma4(o2, a, *(const float4*)&Ks[s][d0+8]);
        fma4(o3, a, *(const float4*)&Ks[s][d0+12]);
    }
    float r = dinv[t];
    float vals[16] = {o0.x*r,o0.y*r,o0.z*r,o0.w*r, o1.x*r,o1.y*r,o1.z*r,o1.w*r,
                      o2.x*r,o2.y*r,o2.z*r,o2.w*r, o3.x*r,o3.y*r,o3.z*r,o3.w*r};
    unsigned short hv[16], lv[16];
    #pragma unroll
    for (int j = 0; j < 16; j++){
        hv[j] = bf16_rne(vals[j]);
        float hf = __uint_as_float((unsigned)hv[j] << 16);
        lv[j] = bf16_rne(vals[j] - hf);
    }
    unsigned short* ap = attn_s + (size_t)(row0+t)*KS2 + col0 + d0;
    #pragma unroll
    for (int q = 0; q < 4; q++){
        ushort4 h4 = {hv[q*4],hv[q*4+1],hv[q*4+2],hv[q*4+3]};
        ushort4 l4 = {lv[q*4],lv[q*4+1],lv[q*4+2],lv[q*4+3]};
        *(ushort4*)&ap[q*4] = h4;
        *(ushort4*)&ap[DIMQ + q*4] = l4;
    }
}

// ---------------------------------------------------------------------------
// Kernel 5: out = (attn @ Wo) * gate, split-bf16 MFMA.
// 64x128 tile, 128 threads (2 waves side-by-side in N), grid (128,6) = 768
// blocks = 3 blocks/CU even. Staging: chunk f handled by (wave w, instr j,
// lane) with f = w*K + j*64 + lane so every global_load_lds dest is
// base + lane*16B (HW contract).
// ---------------------------------------------------------------------------
__global__ __launch_bounds__(128, 2)
void gemm_out_mfma(const unsigned short* __restrict__ attn_s,
                   const unsigned short* __restrict__ wot,
                   const float* __restrict__ gws, float* __restrict__ out)
{
    __shared__ unsigned short Ah[64*32];
    __shared__ unsigned short Al[64*32];
    __shared__ unsigned short Bh[128*32];
    __shared__ unsigned short Bl[128*32];

    const int m0 = blockIdx.x * 64;
    const int n0 = blockIdx.y * 128;
    const int tid = threadIdx.x;
    const int lane = tid & 63, w = tid >> 6;
    const int wn = w * 64;
    const int l15 = lane & 15, lq = lane >> 4;

    // A tile: 256 chunks of 16B (64 rows x 4); wave w covers f = w*128+j*64+lane
    const unsigned short* ap[2]; int ad[2];
    #pragma unroll
    for (int j = 0; j < 2; j++){
        int f = w*128 + j*64 + lane;
        ap[j] = attn_s + (size_t)(m0 + (f>>2))*KS2 + (f&3)*8;
        ad[j] = f*8;
    }
    // B tile: 512 chunks (128 rows x 4); wave w covers f = w*256+j*64+lane
    const unsigned short* bp[4]; int bd[4];
    #pragma unroll
    for (int j = 0; j < 4; j++){
        int f = w*256 + j*64 + lane;
        bp[j] = wot + (size_t)(n0 + (f>>2))*KS2 + (f&3)*8;
        bd[j] = f*8;
    }

    f32x4 acc[4][4];
    #pragma unroll
    for (int i = 0; i < 4; i++)
        #pragma unroll
        for (int j = 0; j < 4; j++)
            acc[i][j] = (f32x4){0.f, 0.f, 0.f, 0.f};

    #pragma unroll 1
    for (int ks = 0; ks < 8; ks++){
        const int o = ks*32;
        __syncthreads();
        #pragma unroll
        for (int j = 0; j < 2; j++){
            gload_lds16(ap[j] + o,        &Ah[ad[j]]);
            gload_lds16(ap[j] + DIMQ + o, &Al[ad[j]]);
        }
        #pragma unroll
        for (int j = 0; j < 4; j++){
            gload_lds16(bp[j] + o,        &Bh[bd[j]]);
            gload_lds16(bp[j] + DIMQ + o, &Bl[bd[j]]);
        }
        __syncthreads();

        bf16x8 ah[4], al[4], bh[4], bl[4];
        #pragma unroll
        for (int im = 0; im < 4; im++){
            ah[im] = *(const bf16x8*)&Ah[(im*16 + l15)*32 + lq*8];
            al[im] = *(const bf16x8*)&Al[(im*16 + l15)*32 + lq*8];
        }
        #pragma unroll
        for (int jn = 0; jn < 4; jn++){
            bh[jn] = *(const bf16x8*)&Bh[(wn + jn*16 + l15)*32 + lq*8];
            bl[jn] = *(const bf16x8*)&Bl[(wn + jn*16 + l15)*32 + lq*8];
        }
        #pragma unroll
        for (int im = 0; im < 4; im++)
            #pragma unroll
            for (int jn = 0; jn < 4; jn++){
                acc[im][jn] = __builtin_amdgcn_mfma_f32_16x16x32_bf16(
                    ah[im], bh[jn], acc[im][jn], 0, 0, 0);
                acc[im][jn] = __builtin_amdgcn_mfma_f32_16x16x32_bf16(
                    ah[im], bl[jn], acc[im][jn], 0, 0, 0);
                acc[im][jn] = __builtin_amdgcn_mfma_f32_16x16x32_bf16(
                    al[im], bh[jn], acc[im][jn], 0, 0, 0);
            }
    }

    #pragma unroll
    for (int im = 0; im < 4; im++){
        const int rb = m0 + im*16 + lq*4;
        #pragma unroll
        for (int jn = 0; jn < 4; jn++){
            const int col = n0 + wn + jn*16 + l15;
            f32x4 a = acc[im][jn];
            #pragma unroll
            for (int r = 0; r < 4; r++){
                size_t idx = (size_t)(rb + r)*DM + col;
                out[idx] = a[r] * gws[idx];
            }
        }
    }
}

// ---------------------------------------------------------------------------
extern "C" void kernel_launch(void* const* d_in, const int* in_sizes, int n_in,
                              void* d_out, int out_size, void* d_ws, size_t ws_size,
                              hipStream_t stream)
{
    const float* x  = (const float*)d_in[0];
    const float* Wq = (const float*)d_in[1];
    const float* Wk = (const float*)d_in[2];
    const float* Wv = (const float*)d_in[3];
    const float* Wo = (const float*)d_in[4];
    const float* Wg = (const float*)d_in[5];
    float* out = (float*)d_out;

    float* w    = (float*)d_ws;
    float* qws  = w;                                   // 8192*256 f32
    float* kws  = qws + (size_t)MROWS*DIMQ;            // 8192*256 f32
    float* vws  = kws + (size_t)MROWS*DIMQ;            // 8192*256 f32
    float* gws  = vws + (size_t)MROWS*DIMQ;            // 8192*768 f32
    float* region = gws + (size_t)MROWS*DM;            // reused region (28.5 MB)
    // phase A (projection): xs (24 MB) + wt (4.5 MB)
    unsigned short* xs = (unsigned short*)region;
    unsigned short* wt = xs + (size_t)MROWS*KSPLIT;
    // phase B (attention; xs/wt dead): Sws(8.5) + Pws(8.5) + attn_s(8.4) + wot(0.8)
    float* Sws = region;
    float* Pws = Sws + (size_t)BATCH*HEADS*NCHUNK*STATE;
    unsigned short* attn_s = (unsigned short*)(Pws + (size_t)BATCH*HEADS*NCHUNK*STATE);
    unsigned short* wot = attn_s + (size_t)MROWS*KS2;
    // high-water: 50.3 MB + 28.5 MB = 78.8 MB (same as verified rounds 2-3)

    hipLaunchKernelGGL(prep, dim3(MROWS + 288), dim3(256), 0, stream,
                       x, Wq, Wk, Wv, Wg, xs, wt);
    hipLaunchKernelGGL(gemm_qkvg_mfma, dim3(64,12), dim3(256), 0, stream,
                       xs, wt, qws, kws, vws, gws);
    // wot aliases dead wt/xs space: must launch after gemm_qkvg_mfma
    hipLaunchKernelGGL(split_wo, dim3(12,4), dim3(256), 0, stream, Wo, wot);
    hipLaunchKernelGGL(chunk_state, dim3(BATCH*HEADS*NCHUNK), dim3(256), 0, stream,
                       kws, vws, Sws);
    hipLaunchKernelGGL(prefix_scan, dim3(BATCH*HEADS, 17), dim3(256), 0, stream,
                       Sws, Pws);
    hipLaunchKernelGGL(chunk_out, dim3(BATCH*HEADS*NCHUNK), dim3(256), 0, stream,
                       qws, kws, vws, Pws, attn_s);
    hipLaunchKernelGGL(gemm_out_mfma, dim3(128,6), dim3(128), 0, stream,
                       attn_s, wot, gws, out);
}

// Round 7
// 215.802 us; speedup vs baseline: 1.0412x; 1.0412x over previous
//
#include <hip/hip_runtime.h>
#include <math.h>

#define BATCH 2
#define TSEQ 4096
#define DM 768
#define HEADS 4
#define DHEAD 64
#define DIMQ 256                  // HEADS*DHEAD
#define MROWS (BATCH*TSEQ)        // 8192
#define CHUNK 64
#define NCHUNK (TSEQ/CHUNK)       // 64
#define NBH (BATCH*HEADS)         // 8
#define STATE (DHEAD*DHEAD + DHEAD)  // 4160
#define KSPLIT (DM*2)             // 1536 stored k-cols for x/wt: [hi 768 | lo 768]
#define KS2 (DIMQ*2)              // 512 stored k-cols for attn/wot: [hi 256 | lo 256]

typedef __attribute__((ext_vector_type(8))) short bf16x8;
typedef __attribute__((ext_vector_type(4))) float f32x4;

__device__ __forceinline__ float act_elu1(float x){ return x > 0.f ? x + 1.f : expf(x); }
__device__ __forceinline__ float act_sig(float x){ return 1.f/(1.f + expf(-x)); }

__device__ __forceinline__ void fma4(float4& o, float a, const float4& b){
    o.x = fmaf(a, b.x, o.x); o.y = fmaf(a, b.y, o.y);
    o.z = fmaf(a, b.z, o.z); o.w = fmaf(a, b.w, o.w);
}
__device__ __forceinline__ float comp4(const float4& v, int u){
    return u==0 ? v.x : u==1 ? v.y : u==2 ? v.z : v.w;
}

// round-to-nearest-even fp32 -> bf16
__device__ __forceinline__ unsigned short bf16_rne(float f){
    unsigned u = __float_as_uint(f);
    u += 0x7FFFu + ((u >> 16) & 1u);
    return (unsigned short)(u >> 16);
}

// NOTE: LDS dest is wave-uniform base + lane*16B (m104/m108). Every call site
// must pass a dest whose per-lane address is exactly base + lane*16.
__device__ __forceinline__ void gload_lds16(const void* g, void* l){
    __builtin_amdgcn_global_load_lds(
        (const __attribute__((address_space(1))) unsigned char*)g,
        (__attribute__((address_space(3))) unsigned char*)l, 16, 0, 0);
}

// ---------------------------------------------------------------------------
// Kernel 0: merged prep. Blocks:
//   [0, 8192)     : split x row -> xs [hi 768 | lo 768]
//   [8192, 8480)  : split/transpose Wq|Wk|Wv|Wg 64x64 tile -> wt
// ---------------------------------------------------------------------------
__global__ __launch_bounds__(256)
void prep(const float* __restrict__ x,
          const float* __restrict__ Wq, const float* __restrict__ Wk,
          const float* __restrict__ Wv, const float* __restrict__ Wg,
          unsigned short* __restrict__ xs, unsigned short* __restrict__ wt)
{
    __shared__ float T[64][65];
    const int bid = blockIdx.x;
    const int t = threadIdx.x;

    if (bid < MROWS) {                       // ---- x split ----
        if (t < 192) {
            const int r = bid;
            const int c = t * 4;
            float4 v = *(const float4*)&x[(size_t)r*DM + c];
            float vv[4] = {v.x, v.y, v.z, v.w};
            unsigned short h[4], l[4];
            #pragma unroll
            for (int j = 0; j < 4; j++){
                h[j] = bf16_rne(vv[j]);
                float hf = __uint_as_float((unsigned)h[j] << 16);
                l[j] = bf16_rne(vv[j] - hf);
            }
            ushort4 h4 = {h[0],h[1],h[2],h[3]}, l4 = {l[0],l[1],l[2],l[3]};
            *(ushort4*)&xs[(size_t)r*KSPLIT + c] = h4;
            *(ushort4*)&xs[(size_t)r*KSPLIT + DM + c] = l4;
        }
        return;
    }

    // ---- weight transpose-split ----
    const int i = bid - MROWS;
    const int n0 = (i % 24)*64, k0 = (i / 24)*64;   // 24 n-tiles x 12 k-tiles
    const float* W; int ldw, c0;
    if      (n0 < 256) { W = Wq; ldw = DIMQ; c0 = n0;       }
    else if (n0 < 512) { W = Wk; ldw = DIMQ; c0 = n0 - 256; }
    else if (n0 < 768) { W = Wv; ldw = DIMQ; c0 = n0 - 512; }
    else               { W = Wg; ldw = DM;   c0 = n0 - 768; }

    const int lr = t >> 4, lc = (t & 15) * 4;
    #pragma unroll
    for (int ii = 0; ii < 4; ii++){
        int r = lr + ii*16;
        float4 v = *(const float4*)&W[(size_t)(k0+r)*ldw + c0 + lc];
        T[r][lc+0]=v.x; T[r][lc+1]=v.y; T[r][lc+2]=v.z; T[r][lc+3]=v.w;
    }
    __syncthreads();
    const int rn = t >> 2, kc = (t & 3) * 16;
    unsigned short hb[16], lb[16];
    #pragma unroll
    for (int j = 0; j < 16; j++){
        float f = T[kc+j][rn];
        hb[j] = bf16_rne(f);
        float hf = __uint_as_float((unsigned)hb[j] << 16);
        lb[j] = bf16_rne(f - hf);
    }
    size_t base = (size_t)(n0+rn)*KSPLIT + k0 + kc;
    #pragma unroll
    for (int q = 0; q < 4; q++){
        ushort4 hv = {hb[q*4],hb[q*4+1],hb[q*4+2],hb[q*4+3]};
        ushort4 lv = {lb[q*4],lb[q*4+1],lb[q*4+2],lb[q*4+3]};
        *(ushort4*)&wt[base + q*4] = hv;
        *(ushort4*)&wt[base + DM + q*4] = lv;
    }
}

// ---------------------------------------------------------------------------
// Kernel 1: fused projection GEMM, single-pass cross-product K-loop.
// ---------------------------------------------------------------------------
__global__ __launch_bounds__(256, 2)
void gemm_qkvg_mfma(const unsigned short* __restrict__ xs,
                    const unsigned short* __restrict__ wt,
                    float* __restrict__ qws, float* __restrict__ kws,
                    float* __restrict__ vws, float* __restrict__ gws)
{
    __shared__ unsigned short Ah[128*32];
    __shared__ unsigned short Al[128*32];
    __shared__ unsigned short Bh[128*32];
    __shared__ unsigned short Bl[128*32];

    const int m0 = blockIdx.x * 128;
    const int n0 = blockIdx.y * 128;
    const int tid = threadIdx.x;
    const int lane = tid & 63, w = tid >> 6;
    const int wm = (w & 1) * 64, wn = (w >> 1) * 64;
    const int l15 = lane & 15, lq = lane >> 4;

    const int srow = tid >> 2, scq = tid & 3;
    const unsigned short* xr0 = xs + (size_t)(m0+srow)   * KSPLIT + scq*8;
    const unsigned short* xr1 = xs + (size_t)(m0+srow+64)* KSPLIT + scq*8;
    const unsigned short* br0 = wt + (size_t)(n0+srow)   * KSPLIT + scq*8;
    const unsigned short* br1 = wt + (size_t)(n0+srow+64)* KSPLIT + scq*8;

    f32x4 acc[4][4];
    #pragma unroll
    for (int i = 0; i < 4; i++)
        #pragma unroll
        for (int j = 0; j < 4; j++)
            acc[i][j] = (f32x4){0.f, 0.f, 0.f, 0.f};

    #pragma unroll 1
    for (int ks = 0; ks < 24; ks++){
        const int o = ks*32;
        __syncthreads();
        gload_lds16(xr0 + o,      &Ah[tid*8]);
        gload_lds16(xr1 + o,      &Ah[2048 + tid*8]);
        gload_lds16(xr0 + DM + o, &Al[tid*8]);
        gload_lds16(xr1 + DM + o, &Al[2048 + tid*8]);
        gload_lds16(br0 + o,      &Bh[tid*8]);
        gload_lds16(br1 + o,      &Bh[2048 + tid*8]);
        gload_lds16(br0 + DM + o, &Bl[tid*8]);
        gload_lds16(br1 + DM + o, &Bl[2048 + tid*8]);
        __syncthreads();

        bf16x8 ah[4], al[4], bh[4], bl[4];
        #pragma unroll
        for (int im = 0; im < 4; im++){
            ah[im] = *(const bf16x8*)&Ah[(wm + im*16 + l15)*32 + lq*8];
            al[im] = *(const bf16x8*)&Al[(wm + im*16 + l15)*32 + lq*8];
        }
        #pragma unroll
        for (int jn = 0; jn < 4; jn++){
            bh[jn] = *(const bf16x8*)&Bh[(wn + jn*16 + l15)*32 + lq*8];
            bl[jn] = *(const bf16x8*)&Bl[(wn + jn*16 + l15)*32 + lq*8];
        }
        #pragma unroll
        for (int im = 0; im < 4; im++)
            #pragma unroll
            for (int jn = 0; jn < 4; jn++){
                acc[im][jn] = __builtin_amdgcn_mfma_f32_16x16x32_bf16(
                    ah[im], bh[jn], acc[im][jn], 0, 0, 0);
                acc[im][jn] = __builtin_amdgcn_mfma_f32_16x16x32_bf16(
                    ah[im], bl[jn], acc[im][jn], 0, 0, 0);
                acc[im][jn] = __builtin_amdgcn_mfma_f32_16x16x32_bf16(
                    al[im], bh[jn], acc[im][jn], 0, 0, 0);
            }
    }

    float* dst; int ld, cb, mode;
    const int bj = blockIdx.y;
    if      (bj < 2) { dst = qws; ld = DIMQ; cb = bj*128;       mode = 1; }
    else if (bj < 4) { dst = kws; ld = DIMQ; cb = (bj-2)*128;   mode = 1; }
    else if (bj < 6) { dst = vws; ld = DIMQ; cb = (bj-4)*128;   mode = 0; }
    else             { dst = gws; ld = DM;   cb = (bj-6)*128;   mode = 2; }

    #pragma unroll
    for (int im = 0; im < 4; im++){
        const int rb = m0 + wm + im*16 + lq*4;
        #pragma unroll
        for (int jn = 0; jn < 4; jn++){
            const int col = cb + wn + jn*16 + l15;
            f32x4 a = acc[im][jn];
            #pragma unroll
            for (int r = 0; r < 4; r++){
                float v0 = a[r];
                float vv = (mode == 1) ? act_elu1(v0)
                         : (mode == 2) ? act_sig(v0) : v0;
                dst[(size_t)(rb + r)*ld + col] = vv;
            }
        }
    }
}

// ---------------------------------------------------------------------------
// Kernel 2: chunk_state (blocks [0,512)) + split_wo (blocks [512,560)).
// chunk_state: S[e][d] = sum_s v[s][e]*k[s][d], z[e] = sum_s k[s][e].
// split_wo: wot row n = [hi(Wo[:,n]) 256 | lo 256]; wot aliases dead wt space,
// so this kernel must run after gemm_qkvg_mfma (it does: needs kws/vws anyway).
// ---------------------------------------------------------------------------
__global__ __launch_bounds__(256, 2)
void chunk_state_wo(const float* __restrict__ kws, const float* __restrict__ vws,
                    float* __restrict__ Sws,
                    const float* __restrict__ Wo, unsigned short* __restrict__ wot)
{
    __shared__ float Ks[64][64];
    __shared__ float Vt[64][68];
    __shared__ float T[64][65];

    const int blk = blockIdx.x;
    const int tid = threadIdx.x;

    if (blk >= NBH*NCHUNK) {                 // ---- split_wo tile ----
        const int i = blk - NBH*NCHUNK;
        const int n0 = (i % 12)*64, k0 = (i / 12)*64;
        const int lr = tid >> 4, lc = (tid & 15) * 4;
        #pragma unroll
        for (int ii = 0; ii < 4; ii++){
            int r = lr + ii*16;
            float4 v = *(const float4*)&Wo[(size_t)(k0+r)*DM + n0 + lc];
            T[r][lc+0]=v.x; T[r][lc+1]=v.y; T[r][lc+2]=v.z; T[r][lc+3]=v.w;
        }
        __syncthreads();
        const int rn = tid >> 2, kc = (tid & 3) * 16;
        unsigned short hb[16], lb[16];
        #pragma unroll
        for (int j = 0; j < 16; j++){
            float f = T[kc+j][rn];
            hb[j] = bf16_rne(f);
            float hf = __uint_as_float((unsigned)hb[j] << 16);
            lb[j] = bf16_rne(f - hf);
        }
        size_t base = (size_t)(n0+rn)*KS2 + k0 + kc;
        #pragma unroll
        for (int q = 0; q < 4; q++){
            ushort4 hv = {hb[q*4],hb[q*4+1],hb[q*4+2],hb[q*4+3]};
            ushort4 lv = {lb[q*4],lb[q*4+1],lb[q*4+2],lb[q*4+3]};
            *(ushort4*)&wot[base + q*4] = hv;
            *(ushort4*)&wot[base + DIMQ + q*4] = lv;
        }
        return;
    }

    // ---- chunk_state ----
    const int c = blk & (NCHUNK-1);
    const int bh = blk >> 6;
    const int b = bh >> 2, h = bh & 3;
    const int row0 = b*TSEQ + c*CHUNK;
    const int col0 = h*DHEAD;

    #pragma unroll
    for (int i = 0; i < 4; i++) {
        int flat = tid + i*256;
        int s = flat >> 4, dq = flat & 15;
        float4 k4 = *(const float4*)&kws[(size_t)(row0+s)*DIMQ + col0 + dq*4];
        *(float4*)&Ks[s][dq*4] = k4;
        float4 v4 = *(const float4*)&vws[(size_t)(row0+s)*DIMQ + col0 + dq*4];
        Vt[dq*4+0][s] = v4.x; Vt[dq*4+1][s] = v4.y;
        Vt[dq*4+2][s] = v4.z; Vt[dq*4+3][s] = v4.w;
    }
    __syncthreads();

    const int e = tid >> 2, d0 = (tid & 3) * 16;
    float4 a0 = {0,0,0,0}, a1 = {0,0,0,0}, a2 = {0,0,0,0}, a3 = {0,0,0,0};
    for (int s = 0; s < 64; s++) {
        float ve = Vt[e][s];
        fma4(a0, ve, *(const float4*)&Ks[s][d0+0]);
        fma4(a1, ve, *(const float4*)&Ks[s][d0+4]);
        fma4(a2, ve, *(const float4*)&Ks[s][d0+8]);
        fma4(a3, ve, *(const float4*)&Ks[s][d0+12]);
    }
    float* Sp = Sws + (size_t)blk * STATE;
    *(float4*)&Sp[e*64 + d0 + 0]  = a0;
    *(float4*)&Sp[e*64 + d0 + 4]  = a1;
    *(float4*)&Sp[e*64 + d0 + 8]  = a2;
    *(float4*)&Sp[e*64 + d0 + 12] = a3;

    if (tid < 64) {
        float z = 0.f;
        for (int s = 0; s < 64; s++) z += Ks[s][tid];
        Sp[4096 + tid] = z;
    }
}

// ---------------------------------------------------------------------------
// Kernel 3: exclusive prefix over chunks, register-resident.
// One thread per (bh, state-elem) column. All 64 loads are independent
// (issued together, one drain) instead of a 64-deep latency chain.
// ---------------------------------------------------------------------------
__global__ __launch_bounds__(256)
void prefix_scan(const float* __restrict__ Sws, float* __restrict__ Pws)
{
    const int colg = blockIdx.x*256 + threadIdx.x;
    if (colg >= NBH*STATE) return;
    const int bh = colg / STATE;
    const int i = colg - bh*STATE;
    const size_t base = (size_t)bh * NCHUNK * STATE + i;
    const float* sp = Sws + base;
    float* pp = Pws + base;
    float v[NCHUNK];
    #pragma unroll
    for (int c = 0; c < NCHUNK; c++) v[c] = sp[(size_t)c * STATE];
    float run = 0.f;
    #pragma unroll
    for (int c = 0; c < NCHUNK; c++){
        pp[(size_t)c * STATE] = run;
        run += v[c];
    }
}

// ---------------------------------------------------------------------------
// Kernel 4: per-chunk output; denom via Kcum trick:
//   denom_t = Q_t · (zP + Kcum_t),  Kcum_t = sum_{s<=t} K_s
// (replaces the divergent masked QK^T row-sum: -256 ds_read_b128/thread).
// Writes attn as split-bf16 [hi 256 | lo 256].
// ---------------------------------------------------------------------------
__global__ __launch_bounds__(256, 2)
void chunk_out(const float* __restrict__ qws, const float* __restrict__ kws,
               const float* __restrict__ vws, const float* __restrict__ Pws,
               unsigned short* __restrict__ attn_s)
{
    __shared__ float Qs[64][68];
    __shared__ float Ks[64][64];
    __shared__ float VA[64][68];   // V^T first, masked A later
    __shared__ float Ps[64][68];   // Kcum first, P later
    __shared__ float zP[64];
    __shared__ float dpart[64][4];
    __shared__ float dinv[64];

    const int blk = blockIdx.x;
    const int c = blk & (NCHUNK-1);
    const int bh = blk >> 6;
    const int b = bh >> 2, h = bh & 3;
    const int row0 = b*TSEQ + c*CHUNK;
    const int col0 = h*DHEAD;
    const int tid = threadIdx.x;
    const float* Pp = Pws + (size_t)blk * STATE;

    // stage Q, K, V^T
    #pragma unroll
    for (int i = 0; i < 4; i++) {
        int flat = tid + i*256;
        int s = flat >> 4, dq = flat & 15;
        float4 q4 = *(const float4*)&qws[(size_t)(row0+s)*DIMQ + col0 + dq*4];
        Qs[s][dq*4+0] = q4.x; Qs[s][dq*4+1] = q4.y;
        Qs[s][dq*4+2] = q4.z; Qs[s][dq*4+3] = q4.w;
        float4 k4 = *(const float4*)&kws[(size_t)(row0+s)*DIMQ + col0 + dq*4];
        *(float4*)&Ks[s][dq*4] = k4;
        float4 v4 = *(const float4*)&vws[(size_t)(row0+s)*DIMQ + col0 + dq*4];
        VA[dq*4+0][s] = v4.x; VA[dq*4+1][s] = v4.y;
        VA[dq*4+2][s] = v4.z; VA[dq*4+3][s] = v4.w;
    }
    __syncthreads();

    // (a) Kcum (inclusive prefix of K rows over s) into Ps; load zP
    if (tid < 64) {
        float run = 0.f;
        for (int s = 0; s < 64; s++){ run += Ks[s][tid]; Ps[s][tid] = run; }
    }
    if (tid >= 192 && tid < 208) {
        int q = tid - 192;
        *(float4*)&zP[q*4] = *(const float4*)&Pp[4096 + q*4];
    }
    __syncthreads();

    const int t  = tid >> 2;
    const int qq = tid & 3;
    const int s0 = qq * 16;

    float4 qreg[16];
    #pragma unroll
    for (int eq = 0; eq < 16; eq++) qreg[eq] = *(const float4*)&Qs[t][eq*4];

    // (b) denom partial over features e in [qq*16, qq*16+16)
    {
        float dsum = 0.f;
        #pragma unroll
        for (int j = 0; j < 4; j++){
            int eq = qq*4 + j;
            float4 qv = qreg[eq];
            float4 kc = *(const float4*)&Ps[t][eq*4];
            float4 z4 = *(const float4*)&zP[eq*4];
            dsum = fmaf(qv.x, kc.x + z4.x, dsum);
            dsum = fmaf(qv.y, kc.y + z4.y, dsum);
            dsum = fmaf(qv.z, kc.z + z4.z, dsum);
            dsum = fmaf(qv.w, kc.w + z4.w, dsum);
        }
        dpart[t][qq] = dsum;
    }

    // (c) A[t][s0+i] = Q[t]·V[s0+i]  (V^T in VA)
    float areg[16];
    #pragma unroll
    for (int i = 0; i < 16; i++) areg[i] = 0.f;
    #pragma unroll
    for (int eq = 0; eq < 16; eq++) {
        float4 qv = qreg[eq];
        #pragma unroll
        for (int u = 0; u < 4; u++) {
            int e = eq*4 + u;
            float qe = comp4(qv, u);
            float4 v0 = *(const float4*)&VA[e][s0+0];
            float4 v1 = *(const float4*)&VA[e][s0+4];
            float4 v2 = *(const float4*)&VA[e][s0+8];
            float4 v3 = *(const float4*)&VA[e][s0+12];
            areg[0]=fmaf(qe,v0.x,areg[0]);  areg[1]=fmaf(qe,v0.y,areg[1]);
            areg[2]=fmaf(qe,v0.z,areg[2]);  areg[3]=fmaf(qe,v0.w,areg[3]);
            areg[4]=fmaf(qe,v1.x,areg[4]);  areg[5]=fmaf(qe,v1.y,areg[5]);
            areg[6]=fmaf(qe,v1.z,areg[6]);  areg[7]=fmaf(qe,v1.w,areg[7]);
            areg[8]=fmaf(qe,v2.x,areg[8]);  areg[9]=fmaf(qe,v2.y,areg[9]);
            areg[10]=fmaf(qe,v2.z,areg[10]); areg[11]=fmaf(qe,v2.w,areg[11]);
            areg[12]=fmaf(qe,v3.x,areg[12]); areg[13]=fmaf(qe,v3.y,areg[13]);
            areg[14]=fmaf(qe,v3.z,areg[14]); areg[15]=fmaf(qe,v3.w,areg[15]);
        }
    }
    __syncthreads();   // V^T and Kcum reads done

    // (d) masked A over VA; dinv; load P into Ps
    #pragma unroll
    for (int i4 = 0; i4 < 4; i4++) {
        float4 wv;
        wv.x = (s0 + i4*4 + 0 <= t) ? areg[i4*4+0] : 0.f;
        wv.y = (s0 + i4*4 + 1 <= t) ? areg[i4*4+1] : 0.f;
        wv.z = (s0 + i4*4 + 2 <= t) ? areg[i4*4+2] : 0.f;
        wv.w = (s0 + i4*4 + 3 <= t) ? areg[i4*4+3] : 0.f;
        *(float4*)&VA[t][s0 + i4*4] = wv;
    }
    if (qq == 0) {
        float den = dpart[t][0] + dpart[t][1] + dpart[t][2] + dpart[t][3];
        den = fmaxf(den, 1e-6f);
        dinv[t] = 1.f / den;
    }
    #pragma unroll
    for (int i = 0; i < 4; i++) {
        int flat = (tid + i*256) * 4;      // element index, step 4
        int e = flat >> 6, d = flat & 63;
        *(float4*)&Ps[e][d] = *(const float4*)&Pp[flat];
    }
    __syncthreads();

    // (e) out[t][d0+j] = (Q·P + maskedA·K) * dinv; split-bf16 store
    const int d0 = qq * 16;
    float4 o0 = {0,0,0,0}, o1 = {0,0,0,0}, o2 = {0,0,0,0}, o3 = {0,0,0,0};
    #pragma unroll
    for (int eq = 0; eq < 16; eq++) {
        float4 qv = qreg[eq];
        #pragma unroll
        for (int u = 0; u < 4; u++) {
            int e = eq*4 + u;
            float qe = comp4(qv, u);
            fma4(o0, qe, *(const float4*)&Ps[e][d0+0]);
            fma4(o1, qe, *(const float4*)&Ps[e][d0+4]);
            fma4(o2, qe, *(const float4*)&Ps[e][d0+8]);
            fma4(o3, qe, *(const float4*)&Ps[e][d0+12]);
        }
    }
    for (int s = 0; s < 64; s++) {
        float a = VA[t][s];
        fma4(o0, a, *(const float4*)&Ks[s][d0+0]);
        fma4(o1, a, *(const float4*)&Ks[s][d0+4]);
        fma4(o2, a, *(const float4*)&Ks[s][d0+8]);
        fma4(o3, a, *(const float4*)&Ks[s][d0+12]);
    }
    float r = dinv[t];
    float vals[16] = {o0.x*r,o0.y*r,o0.z*r,o0.w*r, o1.x*r,o1.y*r,o1.z*r,o1.w*r,
                      o2.x*r,o2.y*r,o2.z*r,o2.w*r, o3.x*r,o3.y*r,o3.z*r,o3.w*r};
    unsigned short hv[16], lv[16];
    #pragma unroll
    for (int j = 0; j < 16; j++){
        hv[j] = bf16_rne(vals[j]);
        float hf = __uint_as_float((unsigned)hv[j] << 16);
        lv[j] = bf16_rne(vals[j] - hf);
    }
    unsigned short* apw = attn_s + (size_t)(row0+t)*KS2 + col0 + d0;
    #pragma unroll
    for (int q = 0; q < 4; q++){
        ushort4 h4 = {hv[q*4],hv[q*4+1],hv[q*4+2],hv[q*4+3]};
        ushort4 l4 = {lv[q*4],lv[q*4+1],lv[q*4+2],lv[q*4+3]};
        *(ushort4*)&apw[q*4] = h4;
        *(ushort4*)&apw[DIMQ + q*4] = l4;
    }
}

// ---------------------------------------------------------------------------
// Kernel 5: out = (attn @ Wo) * gate, split-bf16 MFMA, 128x128 tile,
// 256 threads, grid (64,6).
// ---------------------------------------------------------------------------
__global__ __launch_bounds__(256, 2)
void gemm_out_mfma(const unsigned short* __restrict__ attn_s,
                   const unsigned short* __restrict__ wot,
                   const float* __restrict__ gws, float* __restrict__ out)
{
    __shared__ unsigned short Ah[128*32];
    __shared__ unsigned short Al[128*32];
    __shared__ unsigned short Bh[128*32];
    __shared__ unsigned short Bl[128*32];

    const int m0 = blockIdx.x * 128;
    const int n0 = blockIdx.y * 128;
    const int tid = threadIdx.x;
    const int lane = tid & 63, w = tid >> 6;
    const int wm = (w & 1) * 64, wn = (w >> 1) * 64;
    const int l15 = lane & 15, lq = lane >> 4;

    const int srow = tid >> 2, scq = tid & 3;
    const unsigned short* ar0 = attn_s + (size_t)(m0+srow)   * KS2 + scq*8;
    const unsigned short* ar1 = attn_s + (size_t)(m0+srow+64)* KS2 + scq*8;
    const unsigned short* br0 = wot + (size_t)(n0+srow)   * KS2 + scq*8;
    const unsigned short* br1 = wot + (size_t)(n0+srow+64)* KS2 + scq*8;

    f32x4 acc[4][4];
    #pragma unroll
    for (int i = 0; i < 4; i++)
        #pragma unroll
        for (int j = 0; j < 4; j++)
            acc[i][j] = (f32x4){0.f, 0.f, 0.f, 0.f};

    #pragma unroll 1
    for (int ks = 0; ks < 8; ks++){
        const int o = ks*32;
        __syncthreads();
        gload_lds16(ar0 + o,        &Ah[tid*8]);
        gload_lds16(ar1 + o,        &Ah[2048 + tid*8]);
        gload_lds16(ar0 + DIMQ + o, &Al[tid*8]);
        gload_lds16(ar1 + DIMQ + o, &Al[2048 + tid*8]);
        gload_lds16(br0 + o,        &Bh[tid*8]);
        gload_lds16(br1 + o,        &Bh[2048 + tid*8]);
        gload_lds16(br0 + DIMQ + o, &Bl[tid*8]);
        gload_lds16(br1 + DIMQ + o, &Bl[2048 + tid*8]);
        __syncthreads();

        bf16x8 ah[4], al[4], bh[4], bl[4];
        #pragma unroll
        for (int im = 0; im < 4; im++){
            ah[im] = *(const bf16x8*)&Ah[(wm + im*16 + l15)*32 + lq*8];
            al[im] = *(const bf16x8*)&Al[(wm + im*16 + l15)*32 + lq*8];
        }
        #pragma unroll
        for (int jn = 0; jn < 4; jn++){
            bh[jn] = *(const bf16x8*)&Bh[(wn + jn*16 + l15)*32 + lq*8];
            bl[jn] = *(const bf16x8*)&Bl[(wn + jn*16 + l15)*32 + lq*8];
        }
        #pragma unroll
        for (int im = 0; im < 4; im++)
            #pragma unroll
            for (int jn = 0; jn < 4; jn++){
                acc[im][jn] = __builtin_amdgcn_mfma_f32_16x16x32_bf16(
                    ah[im], bh[jn], acc[im][jn], 0, 0, 0);
                acc[im][jn] = __builtin_amdgcn_mfma_f32_16x16x32_bf16(
                    ah[im], bl[jn], acc[im][jn], 0, 0, 0);
                acc[im][jn] = __builtin_amdgcn_mfma_f32_16x16x32_bf16(
                    al[im], bh[jn], acc[im][jn], 0, 0, 0);
            }
    }

    #pragma unroll
    for (int im = 0; im < 4; im++){
        const int rb = m0 + wm + im*16 + lq*4;
        #pragma unroll
        for (int jn = 0; jn < 4; jn++){
            const int col = n0 + wn + jn*16 + l15;
            f32x4 a = acc[im][jn];
            #pragma unroll
            for (int r = 0; r < 4; r++){
                size_t idx = (size_t)(rb + r)*DM + col;
                out[idx] = a[r] * gws[idx];
            }
        }
    }
}

// ---------------------------------------------------------------------------
extern "C" void kernel_launch(void* const* d_in, const int* in_sizes, int n_in,
                              void* d_out, int out_size, void* d_ws, size_t ws_size,
                              hipStream_t stream)
{
    const float* x  = (const float*)d_in[0];
    const float* Wq = (const float*)d_in[1];
    const float* Wk = (const float*)d_in[2];
    const float* Wv = (const float*)d_in[3];
    const float* Wo = (const float*)d_in[4];
    const float* Wg = (const float*)d_in[5];
    float* out = (float*)d_out;

    float* w    = (float*)d_ws;
    float* qws  = w;                                   // 8192*256 f32
    float* kws  = qws + (size_t)MROWS*DIMQ;            // 8192*256 f32
    float* vws  = kws + (size_t)MROWS*DIMQ;            // 8192*256 f32
    float* gws  = vws + (size_t)MROWS*DIMQ;            // 8192*768 f32
    float* region = gws + (size_t)MROWS*DM;            // reused region (28.5 MB)
    // phase A (projection): xs (24 MB) + wt (4.5 MB)
    unsigned short* xs = (unsigned short*)region;
    unsigned short* wt = xs + (size_t)MROWS*KSPLIT;
    // phase B (attention; xs/wt dead): Sws(8.5) + Pws(8.5) + attn_s(8.4) + wot(0.8)
    float* Sws = region;
    float* Pws = Sws + (size_t)NBH*NCHUNK*STATE;
    unsigned short* attn_s = (unsigned short*)(Pws + (size_t)NBH*NCHUNK*STATE);
    unsigned short* wot = attn_s + (size_t)MROWS*KS2;
    // high-water: 50.3 MB + 28.5 MB = 78.8 MB (same as verified rounds 2-5)

    hipLaunchKernelGGL(prep, dim3(MROWS + 288), dim3(256), 0, stream,
                       x, Wq, Wk, Wv, Wg, xs, wt);
    hipLaunchKernelGGL(gemm_qkvg_mfma, dim3(64,12), dim3(256), 0, stream,
                       xs, wt, qws, kws, vws, gws);
    // chunk_state + split_wo merged (wot aliases dead wt space — runs after qkvg)
    hipLaunchKernelGGL(chunk_state_wo, dim3(NBH*NCHUNK + 48), dim3(256), 0, stream,
                       kws, vws, Sws, Wo, wot);
    hipLaunchKernelGGL(prefix_scan, dim3((NBH*STATE + 255)/256), dim3(256), 0, stream,
                       Sws, Pws);
    hipLaunchKernelGGL(chunk_out, dim3(NBH*NCHUNK), dim3(256), 0, stream,
                       qws, kws, vws, Pws, attn_s);
    hipLaunchKernelGGL(gemm_out_mfma, dim3(64,6), dim3(256), 0, stream,
                       attn_s, wot, gws, out);
}